// Round 11
// baseline (600.300 us; speedup 1.0000x reference)
//
#include <hip/hip_runtime.h>
#include <cstdint>
#include <cfloat>
#include <cstddef>

#define C_   128
#define CH   64
#define B_   8
#define S_   6
#define H_   128
#define W_   192
#define HW   (H_*W_)          /* 24576 */
#define SHW  (S_*HW)          /* 147456 */
#define NPIX (B_*SHW)         /* 1179648 */
#define KTOP 100
#define CAP  6144
#define NEGV (-1e9f)
#define EPSV (1e-6f)
#define CPAD 64               /* counts padded: one counter per 256B */
#define NBIN 2048
#define FCAP 4096

// ---------------------------------------------------------------------------
// K0: prep — transpose w1 (CHxC) -> w1t_g (CxCH) + zero padded counts.
// ---------------------------------------------------------------------------
__global__ __launch_bounds__(256) void prep_kernel(
    const float* __restrict__ w1, float* __restrict__ w1t_g,
    int* __restrict__ counts)
{
    const int i = blockIdx.x * 256 + threadIdx.x;   // grid covers C_*CH = 8192
    if (i < C_ * CH) {
        const int c = i >> 6;           // [0,128)
        const int o = i & (CH - 1);     // [0,64)
        w1t_g[i] = w1[o * C_ + c];
    }
    if (i < B_ * CPAD) counts[i] = 0;
}

// ---------------------------------------------------------------------------
// K1 v5: resp = sigma^2 * ( w2 . relu(W1 @ feat + b1) + b2 )
// Round 11: w-reads split across BOTH fast pipes to unblock the VALU:
//   o in [0,32):  LDS copy (16KB, broadcast ds_read_b128, conflict-free)
//   o in [32,64): scalar-pipe uniform loads; 16KB working set FITS the
//                 16KB scalar L1 (the full 32KB w1t thrashed it every
//                 c-sweep -> per-iter L2 re-misses = the R9-R10 stall).
// Per-pixel FMA chain unchanged (o ascending 0..63, c ascending) =>
// bit-exact, absmax stays 0. 1 px/thread (R9). NO min-waves launch_bounds
// (R6 spill pitfall); spill tripwire = WRITE_SIZE ballooning.
// ---------------------------------------------------------------------------
__global__ __launch_bounds__(256) void resp_kernel(
    const float* __restrict__ feats, const float* __restrict__ sigma,
    const float* __restrict__ w1t_g, const float* __restrict__ b1,
    const float* __restrict__ w2, const float* __restrict__ b2,
    float* __restrict__ resp)
{
    __shared__ float w1l[C_ * 32];      // [c][o<32], 16 KB
    __shared__ float b1s[CH];
    __shared__ float w2s[CH];

    for (int i = threadIdx.x; i < C_ * 32; i += 256) {
        const int c = i >> 5;
        const int o = i & 31;
        w1l[i] = w1t_g[(c << 6) + o];
    }
    if (threadIdx.x < CH) {
        b1s[threadIdx.x] = b1[threadIdx.x];
        w2s[threadIdx.x] = w2[threadIdx.x];
    }
    __syncthreads();

    const int plane = blockIdx.x / 96;              // b*S + s   (96 blk/plane)
    const int p0    = (blockIdx.x % 96) * 256 + threadIdx.x;
    const float* fp = feats + (size_t)plane * (size_t)(C_ * HW) + p0;

    float acc[CH];
#pragma unroll
    for (int o = 0; o < CH; ++o) acc[o] = 0.f;

#pragma unroll 4
    for (int c = 0; c < C_; ++c) {
        const float f = fp[(size_t)c * HW];         // wave: 64x4B contiguous
        const float* wl  = &w1l[c << 5];            // LDS half
        const float* wsg = &w1t_g[(c << 6) + 32];   // scalar half (16KB set)
#pragma unroll
        for (int o = 0; o < 32; o += 4) {           // o = 0..31 from LDS
            const float4 w = *reinterpret_cast<const float4*>(&wl[o]);
            acc[o + 0] += w.x * f;
            acc[o + 1] += w.y * f;
            acc[o + 2] += w.z * f;
            acc[o + 3] += w.w * f;
        }
#pragma unroll
        for (int o = 0; o < 32; o += 4) {           // o = 32..63 from sALU
            const float4 w = *reinterpret_cast<const float4*>(&wsg[o]);
            acc[32 + o + 0] += w.x * f;
            acc[32 + o + 1] += w.y * f;
            acc[32 + o + 2] += w.z * f;
            acc[32 + o + 3] += w.w * f;
        }
    }

    const float b2v = b2[0];
    float rx = b2v;
#pragma unroll
    for (int o = 0; o < CH; ++o) {
        const float hx = fmaxf(acc[o] + b1s[o], 0.f);
        rx += w2s[o] * hx;
    }
    const int   s   = plane % S_;
    const float sg  = sigma[s];
    resp[(size_t)plane * HW + p0] = rx * (sg * sg);
}

// ---------------------------------------------------------------------------
// K2: 3x3x3 local max -> candidates. Per-block LDS aggregation, ONE global
// atomic per block, counters padded to separate cache lines (Round-5 fix).
// ---------------------------------------------------------------------------
__global__ __launch_bounds__(256) void peak_kernel(
    const float* __restrict__ resp, int* __restrict__ counts,
    float* __restrict__ cscore, int* __restrict__ cidx)
{
    __shared__ int   lcount;
    __shared__ int   lbase;
    __shared__ float lsc[256];
    __shared__ int   lsi[256];

    if (threadIdx.x == 0) lcount = 0;
    __syncthreads();

    const int gid = blockIdx.x * 256 + threadIdx.x;   // grid covers NPIX exactly
    const int b   = gid / SHW;                        // uniform per block
    const int rem = gid - b * SHW;
    const int s   = rem / HW;                         // uniform per block
    const int p   = rem - s * HW;
    const int y   = p / W_;
    const int x   = p - y * W_;

    const float v = resp[gid];
    bool win = false;
    if (v > 0.f) {                         // is_peak requires resp > 0
        float m = NEGV;
        for (int ds = -1; ds <= 1; ++ds) {
            const int ss = s + ds;
            if (ss < 0 || ss >= S_) continue;   // NEG padding contributes nothing
            for (int dy = -1; dy <= 1; ++dy) {
                const int yy = y + dy;
                if (yy < 0 || yy >= H_) continue;
                for (int dx = -1; dx <= 1; ++dx) {
                    const int xx = x + dx;
                    if (xx < 0 || xx >= W_) continue;
                    m = fmaxf(m, resp[(b * S_ + ss) * HW + yy * W_ + xx]);
                }
            }
        }
        // m includes v itself, so m >= v and |v - m| = m - v
        win = (m - v < EPSV);
    }

    if (win) {
        const int lp = atomicAdd(&lcount, 1);   // LDS atomic — cheap
        lsc[lp] = v;
        lsi[lp] = s * HW + p;
    }
    __syncthreads();
    if (threadIdx.x == 0 && lcount > 0)
        lbase = atomicAdd(&counts[b * CPAD], lcount);  // one atomic/block, padded line
    __syncthreads();
    const int n = lcount;
    for (int i = threadIdx.x; i < n; i += 256) {
        const int pos = lbase + i;
        if (pos < CAP) {
            cscore[b * CAP + pos] = lsc[i];
            cidx[b * CAP + pos]   = lsi[i];
        }
    }
}

// ---------------------------------------------------------------------------
// K3 v3: histogram radix-select with parallel Stage-B (Round-10 win).
// Exact lax.top_k semantics: (score desc, flat idx asc).
// ---------------------------------------------------------------------------
__global__ __launch_bounds__(256) void topk_kernel(
    const float* __restrict__ cscore, const int* __restrict__ cidx,
    const int* __restrict__ counts, const float* __restrict__ sigma,
    float* __restrict__ out)
{
    __shared__ int   hist[NBIN];
    __shared__ int   psum[256];
    __shared__ float fsc[FCAP];
    __shared__ int   fid[FCAP];
    __shared__ int   nf_sh;
    __shared__ int   binB_sh;

    const int b   = blockIdx.x;
    const int tid = threadIdx.x;

    int cnt = counts[b * CPAD];
    if (cnt > CAP) cnt = CAP;
    const int need = cnt < KTOP ? cnt : KTOP;

    for (int i = tid; i < NBIN; i += 256) hist[i] = 0;
    if (tid == 0) { nf_sh = 0; binB_sh = 0; }
    __syncthreads();

    // Stage A: histogram (scores are >0 so float bits are uint-monotone)
    for (int i = tid; i < cnt; i += 256) {
        const unsigned u = __float_as_uint(cscore[b * CAP + i]);
        atomicAdd(&hist[u >> 20], 1);
    }
    __syncthreads();

    // Stage B (parallel): per-thread 8-bin descending chunks + scan;
    // unique crossing thread writes the threshold bin for rank `need`.
    int part = 0;
#pragma unroll
    for (int j = 0; j < 8; ++j) part += hist[2047 - (tid * 8 + j)];
    psum[tid] = part;
    __syncthreads();
    int v = part;
    for (int off = 1; off < 256; off <<= 1) {
        const int add = (tid >= off) ? psum[tid - off] : 0;
        __syncthreads();
        v += add;
        psum[tid] = v;
        __syncthreads();
    }
    const int base = v - part;          // candidates in higher chunks
    if (need > 0 && base < need && need <= v) {
        int cum = base, Bv = 2047 - tid * 8 - 7;
#pragma unroll
        for (int j = 0; j < 8; ++j) {
            const int bin = 2047 - (tid * 8 + j);
            cum += hist[bin];
            if (cum >= need) { Bv = bin; break; }
        }
        binB_sh = Bv;                    // exactly one thread writes
    }
    __syncthreads();
    const int B = binB_sh;

    // Stage C: compact finalists (set-based; LDS-atomic order irrelevant)
    for (int i = tid; i < cnt; i += 256) {
        const float s_ = cscore[b * CAP + i];
        const unsigned u = __float_as_uint(s_);
        if ((int)(u >> 20) >= B) {
            const int p = atomicAdd(&nf_sh, 1);
            if (p < FCAP) { fsc[p] = s_; fid[p] = cidx[b * CAP + i]; }
        }
    }
    __syncthreads();
    int nf = nf_sh;
    if (nf > FCAP) nf = FCAP;

    // Stage D: one wave, exact iterative top-100 over finalists
    if (tid < 64) {
        const int lane = tid;
        for (int k = 0; k < KTOP; ++k) {
            if (k < need) {
                float bs = -FLT_MAX;
                int   bi = 0x7fffffff;
                int   bp = -1;
                for (int i = lane; i < nf; i += 64) {
                    const float s_ = fsc[i];
                    const int   id = fid[i];
                    if (s_ > bs || (s_ == bs && id < bi)) { bs = s_; bi = id; bp = i; }
                }
#pragma unroll
                for (int off = 32; off > 0; off >>= 1) {
                    const float os = __shfl_xor(bs, off);
                    const int   oi = __shfl_xor(bi, off);
                    const int   op = __shfl_xor(bp, off);
                    if (os > bs || (os == bs && oi < bi)) { bs = os; bi = oi; bp = op; }
                }
                // winner slot is only ever scanned by lane (bp&63): same-lane
                // LDS dependency, no cross-lane sync needed
                if (bp >= 0 && (bp & 63) == lane) fsc[bp] = -FLT_MAX;
                if (lane == 0) {
                    const int sidx = bi / HW;
                    const int sp   = bi - sidx * HW;
                    const int yy   = sp / W_;
                    const int xx   = sp - yy * W_;
                    const int sc_c = sidx < 0 ? 0 : (sidx > S_ - 1 ? S_ - 1 : sidx);
                    out[b * KTOP + k]                 = bs > 0.f ? bs : 0.f;
                    out[800 + (b * KTOP + k) * 2 + 0] = (float)xx / (float)W_;
                    out[800 + (b * KTOP + k) * 2 + 1] = (float)yy / (float)H_;
                    out[2400 + b * KTOP + k]          = sigma[sc_c];
                    out[3200 + b * KTOP + k]          = (float)sp;
                }
            } else if (lane == 0) {
                // cnt < 100 fallback (not expected for this input): NEG entries
                int flat = k - cnt; if (flat < 0) flat = 0;
                const int sidx = flat / HW;
                const int sp   = flat - sidx * HW;
                const int yy   = sp / W_;
                const int xx   = sp - yy * W_;
                const int sc_c = sidx < 0 ? 0 : (sidx > S_ - 1 ? S_ - 1 : sidx);
                out[b * KTOP + k]                 = 0.f;
                out[800 + (b * KTOP + k) * 2 + 0] = (float)xx / (float)W_;
                out[800 + (b * KTOP + k) * 2 + 1] = (float)yy / (float)H_;
                out[2400 + b * KTOP + k]          = sigma[sc_c];
                out[3200 + b * KTOP + k]          = (float)sp;
            }
        }
    }
}

extern "C" void kernel_launch(void* const* d_in, const int* in_sizes, int n_in,
                              void* d_out, int out_size, void* d_ws, size_t ws_size,
                              hipStream_t stream)
{
    const float* feats = (const float*)d_in[0];
    const float* sigma = (const float*)d_in[1];
    const float* w1    = (const float*)d_in[2];
    const float* b1    = (const float*)d_in[3];
    const float* w2    = (const float*)d_in[4];
    const float* b2    = (const float*)d_in[5];
    float* out = (float*)d_out;

    char* ws = (char*)d_ws;
    float* resp   = (float*)ws;
    int*   counts = (int*)(ws + (size_t)NPIX * 4);                       // B_*CPAD ints
    float* cscore = (float*)(ws + (size_t)NPIX * 4 + (size_t)B_ * CPAD * 4);
    int*   cidx   = (int*)(ws + (size_t)NPIX * 4 + (size_t)B_ * CPAD * 4
                              + (size_t)B_ * CAP * 4);
    float* w1t_g  = (float*)(ws + (size_t)NPIX * 4 + (size_t)B_ * CPAD * 4
                              + (size_t)B_ * CAP * 4 + (size_t)B_ * CAP * 4);

    prep_kernel<<<C_ * CH / 256, 256, 0, stream>>>(w1, w1t_g, counts);
    resp_kernel<<<B_ * S_ * 96, 256, 0, stream>>>(feats, sigma, w1t_g, b1, w2, b2, resp);
    peak_kernel<<<NPIX / 256, 256, 0, stream>>>(resp, counts, cscore, cidx);
    topk_kernel<<<B_, 256, 0, stream>>>(cscore, cidx, counts, sigma, out);
}

// Round 12
// 470.184 us; speedup vs baseline: 1.2767x; 1.2767x over previous
//
#include <hip/hip_runtime.h>
#include <cstdint>
#include <cfloat>
#include <cstddef>

#define C_   128
#define CH   64
#define B_   8
#define S_   6
#define H_   128
#define W_   192
#define HW   (H_*W_)          /* 24576 */
#define SHW  (S_*HW)          /* 147456 */
#define NPIX (B_*SHW)         /* 1179648 */
#define KTOP 100
#define CAP  6144
#define NEGV (-1e9f)
#define EPSV (1e-6f)
#define CPAD 64               /* counts padded: one counter per 256B */
#define NBIN 2048
#define FCAP 4096

// ---------------------------------------------------------------------------
// K0: prep — transpose w1 (CHxC) -> w1t_g (CxCH) + zero padded counts.
// ---------------------------------------------------------------------------
__global__ __launch_bounds__(256) void prep_kernel(
    const float* __restrict__ w1, float* __restrict__ w1t_g,
    int* __restrict__ counts)
{
    const int i = blockIdx.x * 256 + threadIdx.x;   // grid covers C_*CH = 8192
    if (i < C_ * CH) {
        const int c = i >> 6;           // [0,128)
        const int o = i & (CH - 1);     // [0,64)
        w1t_g[i] = w1[o * C_ + c];
    }
    if (i < B_ * CPAD) counts[i] = 0;
}

// ---------------------------------------------------------------------------
// K1 v6 (Round 12): block = 128 px x 64 o, 4 waves; wave r owns o-range
// [16r,16r+16). Per c-iter per wave: 4 broadcast ds_read_b128 (w) + 1
// ds_read_b64 (px pair) ~= 54cy LDS vs 64cy VALU (32 FMA) -> VALU-limited.
// (R7 layout needed 16 b128/c = LDS-pipe-bound; R9 scalar path thrashed
// sL1; R11 mixed smem+lds -> shared lgkmcnt serialization. This uses LDS
// ONLY.) f staged in 8KB tiles, issue-early/write-late overlap. Epilogue
// dumps acc to LDS (reusing w region after barrier) and sums o=0..63
// ascending per pixel -> bit-exact same chain as the absmax=0 R9 kernel.
// NO min-waves launch_bounds (R6 spill). Spill tripwire: WRITE_SIZE.
// ---------------------------------------------------------------------------
__global__ __launch_bounds__(256) void resp_kernel(
    const float* __restrict__ feats, const float* __restrict__ sigma,
    const float* __restrict__ w1t_g, const float* __restrict__ b1,
    const float* __restrict__ w2, const float* __restrict__ b2,
    float* __restrict__ resp)
{
    __shared__ float wbuf[C_ * CH];     // 32 KB  [c][o]; reused as acc[o][128px]
    __shared__ float fbuf[16 * 128];    // 8 KB   [cl][px]
    __shared__ float b1s[CH];
    __shared__ float w2s[CH];

    const int tid  = threadIdx.x;
    const int lane = tid & 63;
    const int role = tid >> 6;          // wave id -> o-range
    const int o0   = role * 16;

    // stage all of w into LDS (once), plus b1/w2
    {
        const float4* src = reinterpret_cast<const float4*>(w1t_g);
        float4* dst = reinterpret_cast<float4*>(wbuf);
#pragma unroll
        for (int k = 0; k < 8; ++k) dst[tid + k * 256] = src[tid + k * 256];
    }
    if (tid < CH) { b1s[tid] = b1[tid]; w2s[tid] = w2[tid]; }

    const int plane = blockIdx.x / 192;             // b*S + s
    const int p0    = (blockIdx.x % 192) * 128;
    const float* fp = feats + (size_t)plane * (size_t)(C_ * HW) + p0;

    const int r0 = tid >> 5;            // staging row of this thread (0..7)
    const int cc = (tid & 31) * 4;      // staging col (float index)

    // stage f tile 0 (c rows 0..15)
    {
        const float4 s0 = *reinterpret_cast<const float4*>(fp + (size_t)r0 * HW + cc);
        const float4 s1 = *reinterpret_cast<const float4*>(fp + (size_t)(r0 + 8) * HW + cc);
        reinterpret_cast<float4*>(fbuf)[tid]       = s0;
        reinterpret_cast<float4*>(fbuf)[tid + 256] = s1;
    }
    __syncthreads();                    // w + tile0 staged

    float acc[16][2];
#pragma unroll
    for (int oo = 0; oo < 16; ++oo) { acc[oo][0] = 0.f; acc[oo][1] = 0.f; }

    for (int t = 0; t < 8; ++t) {
        float4 n0, n1;
        if (t < 7) {                    // issue next-tile loads EARLY (T14)
            const float* nb = fp + (size_t)(t + 1) * 16 * HW;
            n0 = *reinterpret_cast<const float4*>(nb + (size_t)r0 * HW + cc);
            n1 = *reinterpret_cast<const float4*>(nb + (size_t)(r0 + 8) * HW + cc);
        }
#pragma unroll
        for (int cl = 0; cl < 16; ++cl) {
            const float2 f2 = *reinterpret_cast<const float2*>(
                fbuf + cl * 128 + 2 * lane);
            const float* wc = wbuf + (t * 16 + cl) * 64 + o0;   // uniform addr
#pragma unroll
            for (int oo = 0; oo < 16; oo += 4) {
                const float4 w = *reinterpret_cast<const float4*>(wc + oo);
                acc[oo + 0][0] += w.x * f2.x;  acc[oo + 0][1] += w.x * f2.y;
                acc[oo + 1][0] += w.y * f2.x;  acc[oo + 1][1] += w.y * f2.y;
                acc[oo + 2][0] += w.z * f2.x;  acc[oo + 2][1] += w.z * f2.y;
                acc[oo + 3][0] += w.w * f2.x;  acc[oo + 3][1] += w.w * f2.y;
            }
        }
        __syncthreads();                // all reads of fbuf done
        if (t < 7) {
            reinterpret_cast<float4*>(fbuf)[tid]       = n0;
            reinterpret_cast<float4*>(fbuf)[tid + 256] = n1;
        }
        __syncthreads();                // next tile visible
    }

    // dump acc into wbuf reused as [o][128px] (w reads all completed +
    // barrier-separated above)
#pragma unroll
    for (int oo = 0; oo < 16; ++oo) {
        float2 v; v.x = acc[oo][0]; v.y = acc[oo][1];
        *reinterpret_cast<float2*>(wbuf + (o0 + oo) * 128 + 2 * lane) = v;
    }
    __syncthreads();

    if (tid < 128) {                    // exact-order epilogue per pixel
        float rx = b2[0];
#pragma unroll
        for (int o = 0; o < CH; ++o) {
            const float hx = fmaxf(wbuf[o * 128 + tid] + b1s[o], 0.f);
            rx += w2s[o] * hx;
        }
        const int   s  = plane % S_;
        const float sg = sigma[s];
        resp[(size_t)plane * HW + p0 + tid] = rx * (sg * sg);
    }
}

// ---------------------------------------------------------------------------
// K2: 3x3x3 local max -> candidates. Per-block LDS aggregation, ONE global
// atomic per block, counters padded to separate cache lines (Round-5 fix).
// ---------------------------------------------------------------------------
__global__ __launch_bounds__(256) void peak_kernel(
    const float* __restrict__ resp, int* __restrict__ counts,
    float* __restrict__ cscore, int* __restrict__ cidx)
{
    __shared__ int   lcount;
    __shared__ int   lbase;
    __shared__ float lsc[256];
    __shared__ int   lsi[256];

    if (threadIdx.x == 0) lcount = 0;
    __syncthreads();

    const int gid = blockIdx.x * 256 + threadIdx.x;   // grid covers NPIX exactly
    const int b   = gid / SHW;                        // uniform per block
    const int rem = gid - b * SHW;
    const int s   = rem / HW;                         // uniform per block
    const int p   = rem - s * HW;
    const int y   = p / W_;
    const int x   = p - y * W_;

    const float v = resp[gid];
    bool win = false;
    if (v > 0.f) {                         // is_peak requires resp > 0
        float m = NEGV;
        for (int ds = -1; ds <= 1; ++ds) {
            const int ss = s + ds;
            if (ss < 0 || ss >= S_) continue;   // NEG padding contributes nothing
            for (int dy = -1; dy <= 1; ++dy) {
                const int yy = y + dy;
                if (yy < 0 || yy >= H_) continue;
                for (int dx = -1; dx <= 1; ++dx) {
                    const int xx = x + dx;
                    if (xx < 0 || xx >= W_) continue;
                    m = fmaxf(m, resp[(b * S_ + ss) * HW + yy * W_ + xx]);
                }
            }
        }
        // m includes v itself, so m >= v and |v - m| = m - v
        win = (m - v < EPSV);
    }

    if (win) {
        const int lp = atomicAdd(&lcount, 1);   // LDS atomic — cheap
        lsc[lp] = v;
        lsi[lp] = s * HW + p;
    }
    __syncthreads();
    if (threadIdx.x == 0 && lcount > 0)
        lbase = atomicAdd(&counts[b * CPAD], lcount);  // one atomic/block, padded line
    __syncthreads();
    const int n = lcount;
    for (int i = threadIdx.x; i < n; i += 256) {
        const int pos = lbase + i;
        if (pos < CAP) {
            cscore[b * CAP + pos] = lsc[i];
            cidx[b * CAP + pos]   = lsi[i];
        }
    }
}

// ---------------------------------------------------------------------------
// K3 v3: histogram radix-select with parallel Stage-B (Round-10 win).
// Exact lax.top_k semantics: (score desc, flat idx asc).
// ---------------------------------------------------------------------------
__global__ __launch_bounds__(256) void topk_kernel(
    const float* __restrict__ cscore, const int* __restrict__ cidx,
    const int* __restrict__ counts, const float* __restrict__ sigma,
    float* __restrict__ out)
{
    __shared__ int   hist[NBIN];
    __shared__ int   psum[256];
    __shared__ float fsc[FCAP];
    __shared__ int   fid[FCAP];
    __shared__ int   nf_sh;
    __shared__ int   binB_sh;

    const int b   = blockIdx.x;
    const int tid = threadIdx.x;

    int cnt = counts[b * CPAD];
    if (cnt > CAP) cnt = CAP;
    const int need = cnt < KTOP ? cnt : KTOP;

    for (int i = tid; i < NBIN; i += 256) hist[i] = 0;
    if (tid == 0) { nf_sh = 0; binB_sh = 0; }
    __syncthreads();

    // Stage A: histogram (scores are >0 so float bits are uint-monotone)
    for (int i = tid; i < cnt; i += 256) {
        const unsigned u = __float_as_uint(cscore[b * CAP + i]);
        atomicAdd(&hist[u >> 20], 1);
    }
    __syncthreads();

    // Stage B (parallel): per-thread 8-bin descending chunks + scan;
    // unique crossing thread writes the threshold bin for rank `need`.
    int part = 0;
#pragma unroll
    for (int j = 0; j < 8; ++j) part += hist[2047 - (tid * 8 + j)];
    psum[tid] = part;
    __syncthreads();
    int v = part;
    for (int off = 1; off < 256; off <<= 1) {
        const int add = (tid >= off) ? psum[tid - off] : 0;
        __syncthreads();
        v += add;
        psum[tid] = v;
        __syncthreads();
    }
    const int base = v - part;          // candidates in higher chunks
    if (need > 0 && base < need && need <= v) {
        int cum = base, Bv = 2047 - tid * 8 - 7;
#pragma unroll
        for (int j = 0; j < 8; ++j) {
            const int bin = 2047 - (tid * 8 + j);
            cum += hist[bin];
            if (cum >= need) { Bv = bin; break; }
        }
        binB_sh = Bv;                    // exactly one thread writes
    }
    __syncthreads();
    const int B = binB_sh;

    // Stage C: compact finalists (set-based; LDS-atomic order irrelevant)
    for (int i = tid; i < cnt; i += 256) {
        const float s_ = cscore[b * CAP + i];
        const unsigned u = __float_as_uint(s_);
        if ((int)(u >> 20) >= B) {
            const int p = atomicAdd(&nf_sh, 1);
            if (p < FCAP) { fsc[p] = s_; fid[p] = cidx[b * CAP + i]; }
        }
    }
    __syncthreads();
    int nf = nf_sh;
    if (nf > FCAP) nf = FCAP;

    // Stage D: one wave, exact iterative top-100 over finalists
    if (tid < 64) {
        const int lane = tid;
        for (int k = 0; k < KTOP; ++k) {
            if (k < need) {
                float bs = -FLT_MAX;
                int   bi = 0x7fffffff;
                int   bp = -1;
                for (int i = lane; i < nf; i += 64) {
                    const float s_ = fsc[i];
                    const int   id = fid[i];
                    if (s_ > bs || (s_ == bs && id < bi)) { bs = s_; bi = id; bp = i; }
                }
#pragma unroll
                for (int off = 32; off > 0; off >>= 1) {
                    const float os = __shfl_xor(bs, off);
                    const int   oi = __shfl_xor(bi, off);
                    const int   op = __shfl_xor(bp, off);
                    if (os > bs || (os == bs && oi < bi)) { bs = os; bi = oi; bp = op; }
                }
                // winner slot is only ever scanned by lane (bp&63): same-lane
                // LDS dependency, no cross-lane sync needed
                if (bp >= 0 && (bp & 63) == lane) fsc[bp] = -FLT_MAX;
                if (lane == 0) {
                    const int sidx = bi / HW;
                    const int sp   = bi - sidx * HW;
                    const int yy   = sp / W_;
                    const int xx   = sp - yy * W_;
                    const int sc_c = sidx < 0 ? 0 : (sidx > S_ - 1 ? S_ - 1 : sidx);
                    out[b * KTOP + k]                 = bs > 0.f ? bs : 0.f;
                    out[800 + (b * KTOP + k) * 2 + 0] = (float)xx / (float)W_;
                    out[800 + (b * KTOP + k) * 2 + 1] = (float)yy / (float)H_;
                    out[2400 + b * KTOP + k]          = sigma[sc_c];
                    out[3200 + b * KTOP + k]          = (float)sp;
                }
            } else if (lane == 0) {
                // cnt < 100 fallback (not expected for this input): NEG entries
                int flat = k - cnt; if (flat < 0) flat = 0;
                const int sidx = flat / HW;
                const int sp   = flat - sidx * HW;
                const int yy   = sp / W_;
                const int xx   = sp - yy * W_;
                const int sc_c = sidx < 0 ? 0 : (sidx > S_ - 1 ? S_ - 1 : sidx);
                out[b * KTOP + k]                 = 0.f;
                out[800 + (b * KTOP + k) * 2 + 0] = (float)xx / (float)W_;
                out[800 + (b * KTOP + k) * 2 + 1] = (float)yy / (float)H_;
                out[2400 + b * KTOP + k]          = sigma[sc_c];
                out[3200 + b * KTOP + k]          = (float)sp;
            }
        }
    }
}

extern "C" void kernel_launch(void* const* d_in, const int* in_sizes, int n_in,
                              void* d_out, int out_size, void* d_ws, size_t ws_size,
                              hipStream_t stream)
{
    const float* feats = (const float*)d_in[0];
    const float* sigma = (const float*)d_in[1];
    const float* w1    = (const float*)d_in[2];
    const float* b1    = (const float*)d_in[3];
    const float* w2    = (const float*)d_in[4];
    const float* b2    = (const float*)d_in[5];
    float* out = (float*)d_out;

    char* ws = (char*)d_ws;
    float* resp   = (float*)ws;
    int*   counts = (int*)(ws + (size_t)NPIX * 4);                       // B_*CPAD ints
    float* cscore = (float*)(ws + (size_t)NPIX * 4 + (size_t)B_ * CPAD * 4);
    int*   cidx   = (int*)(ws + (size_t)NPIX * 4 + (size_t)B_ * CPAD * 4
                              + (size_t)B_ * CAP * 4);
    float* w1t_g  = (float*)(ws + (size_t)NPIX * 4 + (size_t)B_ * CPAD * 4
                              + (size_t)B_ * CAP * 4 + (size_t)B_ * CAP * 4);

    prep_kernel<<<C_ * CH / 256, 256, 0, stream>>>(w1, w1t_g, counts);
    resp_kernel<<<B_ * S_ * 192, 256, 0, stream>>>(feats, sigma, w1t_g, b1, w2, b2, resp);
    peak_kernel<<<NPIX / 256, 256, 0, stream>>>(resp, counts, cscore, cidx);
    topk_kernel<<<B_, 256, 0, stream>>>(cscore, cidx, counts, sigma, out);
}

// Round 13
// 434.036 us; speedup vs baseline: 1.3831x; 1.0833x over previous
//
#include <hip/hip_runtime.h>
#include <cstdint>
#include <cfloat>
#include <cstddef>

#define C_   128
#define CH   64
#define B_   8
#define S_   6
#define H_   128
#define W_   192
#define HW   (H_*W_)          /* 24576 */
#define SHW  (S_*HW)          /* 147456 */
#define NPIX (B_*SHW)         /* 1179648 */
#define KTOP 100
#define CAP  6144
#define NEGV (-1e9f)
#define EPSV (1e-6f)
#define CPAD 64               /* counts padded: one counter per 256B */
#define NBIN 2048
#define FCAP 4096

// ---------------------------------------------------------------------------
// K0: prep — transpose w1 (CHxC) -> w1t_g (CxCH) + zero padded counts.
// ---------------------------------------------------------------------------
__global__ __launch_bounds__(256) void prep_kernel(
    const float* __restrict__ w1, float* __restrict__ w1t_g,
    int* __restrict__ counts)
{
    const int i = blockIdx.x * 256 + threadIdx.x;   // grid covers C_*CH = 8192
    if (i < C_ * CH) {
        const int c = i >> 6;           // [0,128)
        const int o = i & (CH - 1);     // [0,64)
        w1t_g[i] = w1[o * C_ + c];
    }
    if (i < B_ * CPAD) counts[i] = 0;
}

// ---------------------------------------------------------------------------
// K1 v7 (Round 13): R9's winning structure (1 px/thread, scalar-pipe w,
// no LDS in hot loop) + o-dimension split into TWO sequential sweeps:
//   sweep 1: o in [0,32)  over all c -> fold into rx, acc freed
//   sweep 2: o in [32,64) over all c -> fold into rx
// Why: (1) 16KB scalar working set per sweep FITS the 16KB sL1 (32KB
// thrashed it cyclically = the R9 stall); (2) acc 64->32 VGPRs => ~8
// waves/SIMD latency hiding. Cost: f read twice (+94us HBM, overlapped).
// Bit-exact: acc chains c-ascending; rx = b2 then o=0..63 ascending —
// identical scalar chain to the absmax=0 R9 kernel. Evidence base:
// scalar+no-LDS+max-waves beats every LDS variant (R5/R7/R11/R12).
// NO min-waves launch_bounds (R6 spill). Spill tripwire: WRITE_SIZE.
// ---------------------------------------------------------------------------
__global__ __launch_bounds__(256) void resp_kernel(
    const float* __restrict__ feats, const float* __restrict__ sigma,
    const float* __restrict__ w1t_g, const float* __restrict__ b1,
    const float* __restrict__ w2, const float* __restrict__ b2,
    float* __restrict__ resp)
{
    __shared__ float b1s[CH];
    __shared__ float w2s[CH];
    if (threadIdx.x < CH) {
        b1s[threadIdx.x] = b1[threadIdx.x];
        w2s[threadIdx.x] = w2[threadIdx.x];
    }
    __syncthreads();

    const int plane = blockIdx.x / 96;              // b*S + s   (96 blk/plane)
    const int p0    = (blockIdx.x % 96) * 256 + threadIdx.x;
    const float* fp = feats + (size_t)plane * (size_t)(C_ * HW) + p0;

    float rx = b2[0];

    // ---- sweep 1: o in [0,32) ----
    {
        float acc[32];
#pragma unroll
        for (int o = 0; o < 32; ++o) acc[o] = 0.f;

#pragma unroll 4
        for (int c = 0; c < C_; ++c) {
            const float f = fp[(size_t)c * HW];     // wave: 64x4B contiguous
#pragma unroll
            for (int o = 0; o < 32; o += 4) {
                const float4 w = *reinterpret_cast<const float4*>(
                    &w1t_g[(c << 6) + o]);          // uniform -> s_load, 16KB set
                acc[o + 0] += w.x * f;
                acc[o + 1] += w.y * f;
                acc[o + 2] += w.z * f;
                acc[o + 3] += w.w * f;
            }
        }
#pragma unroll
        for (int o = 0; o < 32; ++o) {
            const float hx = fmaxf(acc[o] + b1s[o], 0.f);
            rx += w2s[o] * hx;
        }
    }

    // ---- sweep 2: o in [32,64) ----
    {
        float acc[32];
#pragma unroll
        for (int o = 0; o < 32; ++o) acc[o] = 0.f;

#pragma unroll 4
        for (int c = 0; c < C_; ++c) {
            const float f = fp[(size_t)c * HW];
#pragma unroll
            for (int o = 0; o < 32; o += 4) {
                const float4 w = *reinterpret_cast<const float4*>(
                    &w1t_g[(c << 6) + 32 + o]);     // the other 16KB set
                acc[o + 0] += w.x * f;
                acc[o + 1] += w.y * f;
                acc[o + 2] += w.z * f;
                acc[o + 3] += w.w * f;
            }
        }
#pragma unroll
        for (int o = 0; o < 32; ++o) {
            const float hx = fmaxf(acc[o] + b1s[32 + o], 0.f);
            rx += w2s[32 + o] * hx;
        }
    }

    const int   s   = plane % S_;
    const float sg  = sigma[s];
    resp[(size_t)plane * HW + p0] = rx * (sg * sg);
}

// ---------------------------------------------------------------------------
// K2: 3x3x3 local max -> candidates. Per-block LDS aggregation, ONE global
// atomic per block, counters padded to separate cache lines (Round-5 fix).
// ---------------------------------------------------------------------------
__global__ __launch_bounds__(256) void peak_kernel(
    const float* __restrict__ resp, int* __restrict__ counts,
    float* __restrict__ cscore, int* __restrict__ cidx)
{
    __shared__ int   lcount;
    __shared__ int   lbase;
    __shared__ float lsc[256];
    __shared__ int   lsi[256];

    if (threadIdx.x == 0) lcount = 0;
    __syncthreads();

    const int gid = blockIdx.x * 256 + threadIdx.x;   // grid covers NPIX exactly
    const int b   = gid / SHW;                        // uniform per block
    const int rem = gid - b * SHW;
    const int s   = rem / HW;                         // uniform per block
    const int p   = rem - s * HW;
    const int y   = p / W_;
    const int x   = p - y * W_;

    const float v = resp[gid];
    bool win = false;
    if (v > 0.f) {                         // is_peak requires resp > 0
        float m = NEGV;
        for (int ds = -1; ds <= 1; ++ds) {
            const int ss = s + ds;
            if (ss < 0 || ss >= S_) continue;   // NEG padding contributes nothing
            for (int dy = -1; dy <= 1; ++dy) {
                const int yy = y + dy;
                if (yy < 0 || yy >= H_) continue;
                for (int dx = -1; dx <= 1; ++dx) {
                    const int xx = x + dx;
                    if (xx < 0 || xx >= W_) continue;
                    m = fmaxf(m, resp[(b * S_ + ss) * HW + yy * W_ + xx]);
                }
            }
        }
        // m includes v itself, so m >= v and |v - m| = m - v
        win = (m - v < EPSV);
    }

    if (win) {
        const int lp = atomicAdd(&lcount, 1);   // LDS atomic — cheap
        lsc[lp] = v;
        lsi[lp] = s * HW + p;
    }
    __syncthreads();
    if (threadIdx.x == 0 && lcount > 0)
        lbase = atomicAdd(&counts[b * CPAD], lcount);  // one atomic/block, padded line
    __syncthreads();
    const int n = lcount;
    for (int i = threadIdx.x; i < n; i += 256) {
        const int pos = lbase + i;
        if (pos < CAP) {
            cscore[b * CAP + pos] = lsc[i];
            cidx[b * CAP + pos]   = lsi[i];
        }
    }
}

// ---------------------------------------------------------------------------
// K3 v3: histogram radix-select with parallel Stage-B (Round-10 win).
// Exact lax.top_k semantics: (score desc, flat idx asc).
// ---------------------------------------------------------------------------
__global__ __launch_bounds__(256) void topk_kernel(
    const float* __restrict__ cscore, const int* __restrict__ cidx,
    const int* __restrict__ counts, const float* __restrict__ sigma,
    float* __restrict__ out)
{
    __shared__ int   hist[NBIN];
    __shared__ int   psum[256];
    __shared__ float fsc[FCAP];
    __shared__ int   fid[FCAP];
    __shared__ int   nf_sh;
    __shared__ int   binB_sh;

    const int b   = blockIdx.x;
    const int tid = threadIdx.x;

    int cnt = counts[b * CPAD];
    if (cnt > CAP) cnt = CAP;
    const int need = cnt < KTOP ? cnt : KTOP;

    for (int i = tid; i < NBIN; i += 256) hist[i] = 0;
    if (tid == 0) { nf_sh = 0; binB_sh = 0; }
    __syncthreads();

    // Stage A: histogram (scores are >0 so float bits are uint-monotone)
    for (int i = tid; i < cnt; i += 256) {
        const unsigned u = __float_as_uint(cscore[b * CAP + i]);
        atomicAdd(&hist[u >> 20], 1);
    }
    __syncthreads();

    // Stage B (parallel): per-thread 8-bin descending chunks + scan;
    // unique crossing thread writes the threshold bin for rank `need`.
    int part = 0;
#pragma unroll
    for (int j = 0; j < 8; ++j) part += hist[2047 - (tid * 8 + j)];
    psum[tid] = part;
    __syncthreads();
    int v = part;
    for (int off = 1; off < 256; off <<= 1) {
        const int add = (tid >= off) ? psum[tid - off] : 0;
        __syncthreads();
        v += add;
        psum[tid] = v;
        __syncthreads();
    }
    const int base = v - part;          // candidates in higher chunks
    if (need > 0 && base < need && need <= v) {
        int cum = base, Bv = 2047 - tid * 8 - 7;
#pragma unroll
        for (int j = 0; j < 8; ++j) {
            const int bin = 2047 - (tid * 8 + j);
            cum += hist[bin];
            if (cum >= need) { Bv = bin; break; }
        }
        binB_sh = Bv;                    // exactly one thread writes
    }
    __syncthreads();
    const int B = binB_sh;

    // Stage C: compact finalists (set-based; LDS-atomic order irrelevant)
    for (int i = tid; i < cnt; i += 256) {
        const float s_ = cscore[b * CAP + i];
        const unsigned u = __float_as_uint(s_);
        if ((int)(u >> 20) >= B) {
            const int p = atomicAdd(&nf_sh, 1);
            if (p < FCAP) { fsc[p] = s_; fid[p] = cidx[b * CAP + i]; }
        }
    }
    __syncthreads();
    int nf = nf_sh;
    if (nf > FCAP) nf = FCAP;

    // Stage D: one wave, exact iterative top-100 over finalists
    if (tid < 64) {
        const int lane = tid;
        for (int k = 0; k < KTOP; ++k) {
            if (k < need) {
                float bs = -FLT_MAX;
                int   bi = 0x7fffffff;
                int   bp = -1;
                for (int i = lane; i < nf; i += 64) {
                    const float s_ = fsc[i];
                    const int   id = fid[i];
                    if (s_ > bs || (s_ == bs && id < bi)) { bs = s_; bi = id; bp = i; }
                }
#pragma unroll
                for (int off = 32; off > 0; off >>= 1) {
                    const float os = __shfl_xor(bs, off);
                    const int   oi = __shfl_xor(bi, off);
                    const int   op = __shfl_xor(bp, off);
                    if (os > bs || (os == bs && oi < bi)) { bs = os; bi = oi; bp = op; }
                }
                // winner slot is only ever scanned by lane (bp&63): same-lane
                // LDS dependency, no cross-lane sync needed
                if (bp >= 0 && (bp & 63) == lane) fsc[bp] = -FLT_MAX;
                if (lane == 0) {
                    const int sidx = bi / HW;
                    const int sp   = bi - sidx * HW;
                    const int yy   = sp / W_;
                    const int xx   = sp - yy * W_;
                    const int sc_c = sidx < 0 ? 0 : (sidx > S_ - 1 ? S_ - 1 : sidx);
                    out[b * KTOP + k]                 = bs > 0.f ? bs : 0.f;
                    out[800 + (b * KTOP + k) * 2 + 0] = (float)xx / (float)W_;
                    out[800 + (b * KTOP + k) * 2 + 1] = (float)yy / (float)H_;
                    out[2400 + b * KTOP + k]          = sigma[sc_c];
                    out[3200 + b * KTOP + k]          = (float)sp;
                }
            } else if (lane == 0) {
                // cnt < 100 fallback (not expected for this input): NEG entries
                int flat = k - cnt; if (flat < 0) flat = 0;
                const int sidx = flat / HW;
                const int sp   = flat - sidx * HW;
                const int yy   = sp / W_;
                const int xx   = sp - yy * W_;
                const int sc_c = sidx < 0 ? 0 : (sidx > S_ - 1 ? S_ - 1 : sidx);
                out[b * KTOP + k]                 = 0.f;
                out[800 + (b * KTOP + k) * 2 + 0] = (float)xx / (float)W_;
                out[800 + (b * KTOP + k) * 2 + 1] = (float)yy / (float)H_;
                out[2400 + b * KTOP + k]          = sigma[sc_c];
                out[3200 + b * KTOP + k]          = (float)sp;
            }
        }
    }
}

extern "C" void kernel_launch(void* const* d_in, const int* in_sizes, int n_in,
                              void* d_out, int out_size, void* d_ws, size_t ws_size,
                              hipStream_t stream)
{
    const float* feats = (const float*)d_in[0];
    const float* sigma = (const float*)d_in[1];
    const float* w1    = (const float*)d_in[2];
    const float* b1    = (const float*)d_in[3];
    const float* w2    = (const float*)d_in[4];
    const float* b2    = (const float*)d_in[5];
    float* out = (float*)d_out;

    char* ws = (char*)d_ws;
    float* resp   = (float*)ws;
    int*   counts = (int*)(ws + (size_t)NPIX * 4);                       // B_*CPAD ints
    float* cscore = (float*)(ws + (size_t)NPIX * 4 + (size_t)B_ * CPAD * 4);
    int*   cidx   = (int*)(ws + (size_t)NPIX * 4 + (size_t)B_ * CPAD * 4
                              + (size_t)B_ * CAP * 4);
    float* w1t_g  = (float*)(ws + (size_t)NPIX * 4 + (size_t)B_ * CPAD * 4
                              + (size_t)B_ * CAP * 4 + (size_t)B_ * CAP * 4);

    prep_kernel<<<C_ * CH / 256, 256, 0, stream>>>(w1, w1t_g, counts);
    resp_kernel<<<B_ * S_ * 96, 256, 0, stream>>>(feats, sigma, w1t_g, b1, w2, b2, resp);
    peak_kernel<<<NPIX / 256, 256, 0, stream>>>(resp, counts, cscore, cidx);
    topk_kernel<<<B_, 256, 0, stream>>>(cscore, cidx, counts, sigma, out);
}